// Round 1
// baseline (148.841 us; speedup 1.0000x reference)
//
#include <hip/hip_runtime.h>
#include <hip/hip_bf16.h>
#include <stdint.h>

#define M_DIM 8192
#define N_DIM 1024
#define K_DIM 4096
#define BM 128
#define BN 128
#define BK 64

typedef __bf16 bf16x8 __attribute__((ext_vector_type(8)));
typedef float f32x4 __attribute__((ext_vector_type(4)));
typedef __hip_bfloat16 bf16_t;

__device__ __forceinline__ void gload_lds16(const void* g, void* l) {
  __builtin_amdgcn_global_load_lds(
      (const __attribute__((address_space(1))) void*)g,
      (__attribute__((address_space(3))) void*)l, 16, 0, 0);
}

// ---------------- f32 -> bf16 conversion (RNE), 8 elems/thread ----------------
__global__ __launch_bounds__(256) void cvt_f32_bf16(const float* __restrict__ src,
                                                    bf16_t* __restrict__ dst) {
  size_t i = (size_t)blockIdx.x * 256 + threadIdx.x;
  const float4* s = (const float4*)src;
  float4 a = s[2 * i];
  float4 c = s[2 * i + 1];
  union { bf16_t h[8]; int4 v; } u;
  u.h[0] = __float2bfloat16(a.x); u.h[1] = __float2bfloat16(a.y);
  u.h[2] = __float2bfloat16(a.z); u.h[3] = __float2bfloat16(a.w);
  u.h[4] = __float2bfloat16(c.x); u.h[5] = __float2bfloat16(c.y);
  u.h[6] = __float2bfloat16(c.z); u.h[7] = __float2bfloat16(c.w);
  ((int4*)dst)[i] = u.v;
}

// ---------------- bf16 MFMA GEMM: V[M][N] = A[M][K] * Bw[N][K]^T --------------
// m97 structure: 128x128 tile, BK=64, 4 waves (2x2 of 64x64), 16x16x32 bf16,
// global_load_lds width=16, single LDS buffer, 2 barriers per K-step.
__global__ __launch_bounds__(256, 2) void gemm_bt(
    const bf16_t* __restrict__ A,   // enc bf16 [M][K]
    const bf16_t* __restrict__ Bw,  // W   bf16 [N][K]
    float* __restrict__ V) {        // [M][N]
  __shared__ bf16_t As[BM][BK];
  __shared__ bf16_t Bs[BN][BK];

  const int tid  = threadIdx.x;
  const int lane = tid & 63;
  const int wave = tid >> 6;
  const int wr = wave >> 1, wc = wave & 1;

  const int tileM = blockIdx.x >> 3;   // N_DIM/BN == 8 tiles in N
  const int tileN = blockIdx.x & 7;

  const bf16_t* Abase = A  + (size_t)tileM * BM * K_DIM;
  const bf16_t* Bbase = Bw + (size_t)tileN * BN * K_DIM;

  const int srow = tid >> 3;        // 0..31 (row within 32-row staging slab)
  const int scol = (tid & 7) * 8;   // 0..56 (8 bf16 = 16B chunk)

  const int fr = lane & 15;         // M (or N) index within fragment
  const int fk = (lane >> 4) * 8;   // K sub-offset within 32-slice

  f32x4 acc[4][4];
  #pragma unroll
  for (int i = 0; i < 4; ++i)
    #pragma unroll
    for (int j = 0; j < 4; ++j)
      acc[i][j] = (f32x4){0.f, 0.f, 0.f, 0.f};

  for (int kt = 0; kt < K_DIM / BK; ++kt) {
    const bf16_t* Ak = Abase + kt * BK;
    const bf16_t* Bk = Bbase + kt * BK;
    #pragma unroll
    for (int i = 0; i < 4; ++i) {
      int r = i * 32 + srow;
      gload_lds16(Ak + (size_t)r * K_DIM + scol, &As[r][scol]);
      gload_lds16(Bk + (size_t)r * K_DIM + scol, &Bs[r][scol]);
    }
    __syncthreads();   // drains vmcnt(0) before barrier

    #pragma unroll
    for (int kk = 0; kk < 2; ++kk) {
      bf16x8 af[4], bfv[4];
      #pragma unroll
      for (int i = 0; i < 4; ++i)
        af[i] = *(const bf16x8*)&As[wr * 64 + i * 16 + fr][kk * 32 + fk];
      #pragma unroll
      for (int j = 0; j < 4; ++j)
        bfv[j] = *(const bf16x8*)&Bs[wc * 64 + j * 16 + fr][kk * 32 + fk];
      #pragma unroll
      for (int i = 0; i < 4; ++i)
        #pragma unroll
        for (int j = 0; j < 4; ++j)
          acc[i][j] = __builtin_amdgcn_mfma_f32_16x16x32_bf16(af[i], bfv[j], acc[i][j], 0, 0, 0);
    }
    __syncthreads();
  }

  // C/D layout (m89-verified): col = lane&15, row = (lane>>4)*4 + reg
  const int cr0 = tileM * BM + wr * 64 + (lane >> 4) * 4;
  const int cc0 = tileN * BN + wc * 64 + (lane & 15);
  #pragma unroll
  for (int i = 0; i < 4; ++i)
    #pragma unroll
    for (int j = 0; j < 4; ++j) {
      const int r0 = cr0 + i * 16;
      const int c  = cc0 + j * 16;
      #pragma unroll
      for (int r = 0; r < 4; ++r)
        V[(size_t)(r0 + r) * N_DIM + c] = acc[i][j][r];
    }
}

// ---------------- fallback fp32 tiled GEMM (only if ws too small) -------------
__global__ __launch_bounds__(256) void gemm_f32_tiled(
    const float* __restrict__ A, const float* __restrict__ Bw, float* __restrict__ V) {
  __shared__ float As[64][33];
  __shared__ float Bs[64][33];
  const int tid = threadIdx.x;
  const int tx = tid & 15, ty = tid >> 4;
  const int bm = blockIdx.x, bn = blockIdx.y;
  const float* Ab = A  + (size_t)bm * 64 * K_DIM;
  const float* Bb = Bw + (size_t)bn * 64 * K_DIM;
  float acc[4][4] = {};
  for (int kt = 0; kt < K_DIM; kt += 32) {
    #pragma unroll
    for (int i = 0; i < 8; ++i) {
      int r = tid >> 2;
      int c = (tid & 3) * 8 + i;
      As[r][c] = Ab[(size_t)r * K_DIM + kt + c];
      Bs[r][c] = Bb[(size_t)r * K_DIM + kt + c];
    }
    __syncthreads();
    #pragma unroll
    for (int k = 0; k < 32; ++k) {
      float a[4], b[4];
      #pragma unroll
      for (int i = 0; i < 4; ++i) a[i] = As[ty * 4 + i][k];
      #pragma unroll
      for (int j = 0; j < 4; ++j) b[j] = Bs[tx * 4 + j][k];
      #pragma unroll
      for (int i = 0; i < 4; ++i)
        #pragma unroll
        for (int j = 0; j < 4; ++j)
          acc[i][j] += a[i] * b[j];
    }
    __syncthreads();
  }
  #pragma unroll
  for (int i = 0; i < 4; ++i)
    #pragma unroll
    for (int j = 0; j < 4; ++j)
      V[(size_t)(bm * 64 + ty * 4 + i) * N_DIM + bn * 64 + tx * 4 + j] = acc[i][j];
}

// ---------------- Householder epilogue: in-place on d_out ---------------------
// out = x - 2*v*(v.x)/||v||, v = V_row + bias ; one block per row.
__global__ __launch_bounds__(256) void householder_ep(
    const float* __restrict__ x, const float* __restrict__ bias,
    float* __restrict__ vio, float* __restrict__ logdet) {
  const int row = blockIdx.x;
  const int t = threadIdx.x;
  float4* vr = (float4*)(vio + (size_t)row * N_DIM);
  const float4* xr = (const float4*)(x + (size_t)row * N_DIM);
  const float4* br = (const float4*)bias;

  float4 v = vr[t];
  float4 xx = xr[t];
  float4 bb = br[t];
  v.x += bb.x; v.y += bb.y; v.z += bb.z; v.w += bb.w;

  float dot = v.x * xx.x + v.y * xx.y + v.z * xx.z + v.w * xx.w;
  float nsq = v.x * v.x + v.y * v.y + v.z * v.z + v.w * v.w;

  #pragma unroll
  for (int off = 32; off > 0; off >>= 1) {
    dot += __shfl_down(dot, off);
    nsq += __shfl_down(nsq, off);
  }
  __shared__ float sd[4], sn[4];
  if ((t & 63) == 0) { sd[t >> 6] = dot; sn[t >> 6] = nsq; }
  __syncthreads();
  dot = sd[0] + sd[1] + sd[2] + sd[3];
  nsq = sn[0] + sn[1] + sn[2] + sn[3];

  const float f = 2.0f * dot / sqrtf(nsq);
  float4 o;
  o.x = xx.x - f * v.x;
  o.y = xx.y - f * v.y;
  o.z = xx.z - f * v.z;
  o.w = xx.w - f * v.w;
  vr[t] = o;
  if (t == 0) logdet[row] = 0.0f;
}

extern "C" void kernel_launch(void* const* d_in, const int* in_sizes, int n_in,
                              void* d_out, int out_size, void* d_ws, size_t ws_size,
                              hipStream_t stream) {
  const float* x   = (const float*)d_in[0];   // input [8192,1024]
  const float* enc = (const float*)d_in[1];   // encoder_output [8192,4096]
  const float* W   = (const float*)d_in[2];   // W [1024,4096]
  const float* b   = (const float*)d_in[3];   // b [1024]

  float* out    = (float*)d_out;
  float* v      = out;                               // v lives in d_out[0 : M*N)
  float* logdet = out + (size_t)M_DIM * N_DIM;       // [8192]

  const size_t encB_bytes = (size_t)M_DIM * K_DIM * 2;   // 64 MB
  const size_t wB_bytes   = (size_t)N_DIM * K_DIM * 2;   //  8 MB

  if (ws_size >= encB_bytes + wB_bytes) {
    bf16_t* encB = (bf16_t*)d_ws;
    bf16_t* wB   = (bf16_t*)((char*)d_ws + encB_bytes);
    cvt_f32_bf16<<<((size_t)M_DIM * K_DIM) / 8 / 256, 256, 0, stream>>>(enc, encB);
    cvt_f32_bf16<<<((size_t)N_DIM * K_DIM) / 8 / 256, 256, 0, stream>>>(W, wB);
    gemm_bt<<<(M_DIM / BM) * (N_DIM / BN), 256, 0, stream>>>(encB, wB, v);
  } else {
    gemm_f32_tiled<<<dim3(M_DIM / 64, N_DIM / 64), 256, 0, stream>>>(enc, W, v);
  }
  householder_ep<<<M_DIM, 256, 0, stream>>>(x, b, v, logdet);
}

// Round 2
// 134.052 us; speedup vs baseline: 1.1103x; 1.1103x over previous
//
#include <hip/hip_runtime.h>
#include <hip/hip_bf16.h>
#include <stdint.h>

#define M_DIM 8192
#define N_DIM 1024
#define K_DIM 4096

typedef __bf16 bf16x8 __attribute__((ext_vector_type(8)));
typedef float f32x4 __attribute__((ext_vector_type(4)));
typedef __hip_bfloat16 bf16_t;
typedef f32x4 AccT[2][4][2][2];

__device__ __forceinline__ void gload_lds16(const void* g, void* l) {
  __builtin_amdgcn_global_load_lds(
      (const __attribute__((address_space(1))) void*)g,
      (__attribute__((address_space(3))) void*)l, 16, 0, 0);
}

// ---- pack: fp32 [R][4096] -> bf16, tiled [rt][kt][256 rows][8 chunks], with
// the st-swizzle pre-applied (chunk' = chunk ^ (row&7)) so GEMM staging is a
// linear copy and swizzled ds_reads are bank-conflict-free (rule #21).
__global__ __launch_bounds__(256) void pack_swz(const float* __restrict__ src,
                                                int4* __restrict__ dst) {
  const unsigned tid = blockIdx.x * 256 + threadIdx.x;
  const unsigned cp = tid & 7;
  const unsigned tmp = tid >> 3;
  const unsigned r = tmp & 255;
  const unsigned tmp2 = tmp >> 8;
  const unsigned kt = tmp2 & 63;
  const unsigned rt = tmp2 >> 6;
  const unsigned srow = (rt << 8) + r;
  const unsigned k0 = (kt << 6) + ((cp ^ (r & 7)) << 3);
  const float4* s = (const float4*)(src + (size_t)srow * 4096 + k0);
  float4 a = s[0], b = s[1];
  union { bf16_t h[8]; int4 v; } u;
  u.h[0] = __float2bfloat16(a.x); u.h[1] = __float2bfloat16(a.y);
  u.h[2] = __float2bfloat16(a.z); u.h[3] = __float2bfloat16(a.w);
  u.h[4] = __float2bfloat16(b.x); u.h[5] = __float2bfloat16(b.y);
  u.h[6] = __float2bfloat16(b.z); u.h[7] = __float2bfloat16(b.w);
  dst[tid] = u.v;
}

// ---- 8-phase 256x256 GEMM (m201 template, plain HIP) -------------------------
// 512 thr = 8 waves (2M x 4N), per-wave C = 128x64 (interleaved qm/qn halves),
// BK=64, double-buffered LDS 128KB, counted vmcnt (10/4), setprio around MFMA.
__device__ __forceinline__ void stage_half(const char* g, char* smem, int ldsoff, int tid) {
  gload_lds16(g + tid * 16, smem + ldsoff + tid * 16);
  gload_lds16(g + 8192 + tid * 16, smem + ldsoff + 8192 + tid * 16);
}

template <int QM, int QN, int VM>
__device__ __forceinline__ void phase(char* smem, int bb, int wm, int wn,
                                      int lrow, int lkc, int tid,
                                      const char* gsrc, int ldsoff, AccT& acc) {
  bf16x8 af[4][2];
  bf16x8 bfr[2][2];
  const char* ab = smem + bb * 65536;
  #pragma unroll
  for (int f = 0; f < 4; ++f)
    #pragma unroll
    for (int s = 0; s < 2; ++s) {
      int r = QM * 128 + wm * 64 + f * 16 + lrow;
      int c = s * 4 + lkc;
      af[f][s] = *(const bf16x8*)(ab + r * 128 + ((c ^ (r & 7)) << 4));
    }
  #pragma unroll
  for (int f2 = 0; f2 < 2; ++f2)
    #pragma unroll
    for (int s = 0; s < 2; ++s) {
      int r = QN * 128 + wn * 32 + f2 * 16 + lrow;
      int c = s * 4 + lkc;
      bfr[f2][s] = *(const bf16x8*)(ab + 32768 + r * 128 + ((c ^ (r & 7)) << 4));
    }
  stage_half(gsrc, smem, ldsoff, tid);
  __builtin_amdgcn_sched_barrier(0);
  __builtin_amdgcn_s_barrier();
  asm volatile("s_waitcnt lgkmcnt(0)" ::: "memory");
  __builtin_amdgcn_sched_barrier(0);
  __builtin_amdgcn_s_setprio(1);
  #pragma unroll
  for (int f = 0; f < 4; ++f)
    #pragma unroll
    for (int f2 = 0; f2 < 2; ++f2)
      #pragma unroll
      for (int s = 0; s < 2; ++s)
        acc[QM][f][QN][f2] = __builtin_amdgcn_mfma_f32_16x16x32_bf16(
            af[f][s], bfr[f2][s], acc[QM][f][QN][f2], 0, 0, 0);
  __builtin_amdgcn_s_setprio(0);
  if constexpr (VM == 10) asm volatile("s_waitcnt vmcnt(10)" ::: "memory");
  if constexpr (VM == 4)  asm volatile("s_waitcnt vmcnt(4)" ::: "memory");
  __builtin_amdgcn_sched_barrier(0);
  __builtin_amdgcn_s_barrier();
}

__global__ __launch_bounds__(512, 2) void gemm8(
    const char* __restrict__ pA, const char* __restrict__ pB,
    float* __restrict__ V0, float* __restrict__ V1p, int NT) {
  extern __shared__ char smem[];
  const int tid = threadIdx.x;
  const int lane = tid & 63, wave = tid >> 6;
  const int wm = wave >> 2, wn = wave & 3;
  const int lrow = lane & 15, lkc = lane >> 4;

  // XCD-aware swizzle (grid % 8 == 0 always: 128 or 256 blocks)
  const int cpx = (int)gridDim.x >> 3;
  const int swz = ((int)blockIdx.x & 7) * cpx + ((int)blockIdx.x >> 3);
  const int split = swz >> 7;          // 128 blocks per K-split
  const int rem = swz & 127;
  const int mt = rem >> 2, nt = rem & 3;

  const char* Abase = pA + ((size_t)mt * 64 + (size_t)split * NT) * 32768;
  const char* Bbase = pB + ((size_t)nt * 64 + (size_t)split * NT) * 32768;
  float* V = split ? V1p : V0;

  AccT acc;
  #pragma unroll
  for (int a0 = 0; a0 < 2; ++a0)
    #pragma unroll
    for (int a1 = 0; a1 < 4; ++a1)
      #pragma unroll
      for (int a2 = 0; a2 < 2; ++a2)
        #pragma unroll
        for (int a3 = 0; a3 < 2; ++a3)
          acc[a0][a1][a2][a3] = (f32x4){0.f, 0.f, 0.f, 0.f};

  const int ktm = NT - 1;   // NT is 32 or 64 (power of two)

  // Prologue: Ah0(0), Bh1(0), Ah1(0), Bh0(0), Ah0(1), Bh1(1)
  stage_half(Abase, smem, 0, tid);
  stage_half(Bbase + 16384, smem, 32768 + 16384, tid);
  stage_half(Abase + 16384, smem, 16384, tid);
  stage_half(Bbase, smem, 32768, tid);
  stage_half(Abase + 32768, smem, 65536, tid);
  stage_half(Bbase + 32768 + 16384, smem, 65536 + 32768 + 16384, tid);
  asm volatile("s_waitcnt vmcnt(4)" ::: "memory");
  __builtin_amdgcn_s_barrier();

  for (int g = 0; g < NT; ++g) {
    const int bb = g & 1, nbf = bb ^ 1;
    const char* A1t = Abase + (size_t)((g + 1) & ktm) * 32768;
    const char* B1t = Bbase + (size_t)((g + 1) & ktm) * 32768;
    const char* A2t = Abase + (size_t)((g + 2) & ktm) * 32768;
    const char* B2t = Bbase + (size_t)((g + 2) & ktm) * 32768;
    // stage slots: P0->Ah1(g+1), P1->Bh0(g+1), P2->Ah0(g+2), P3->Bh1(g+2)
    phase<0, 0, 0>(smem, bb, wm, wn, lrow, lkc, tid, A1t + 16384, nbf * 65536 + 16384, acc);
    phase<0, 1, 10>(smem, bb, wm, wn, lrow, lkc, tid, B1t, nbf * 65536 + 32768, acc);
    phase<1, 1, 0>(smem, bb, wm, wn, lrow, lkc, tid, A2t, bb * 65536, acc);
    phase<1, 0, 4>(smem, bb, wm, wn, lrow, lkc, tid, B2t + 16384, bb * 65536 + 32768 + 16384, acc);
  }

  // C-write: frag layout col=lane&15, row=(lane>>4)*4+reg (m89-verified)
  const int lq = lane >> 4;
  #pragma unroll
  for (int qm = 0; qm < 2; ++qm)
    #pragma unroll
    for (int f = 0; f < 4; ++f)
      #pragma unroll
      for (int qn = 0; qn < 2; ++qn)
        #pragma unroll
        for (int f2 = 0; f2 < 2; ++f2) {
          const int rowg = mt * 256 + qm * 128 + wm * 64 + f * 16 + lq * 4;
          const int colg = nt * 256 + qn * 128 + wn * 32 + f2 * 16 + lrow;
          #pragma unroll
          for (int reg = 0; reg < 4; ++reg)
            V[(size_t)(rowg + reg) * N_DIM + colg] = acc[qm][f][qn][f2][reg];
        }
}

// ---- Householder epilogue: combines split-K partials, in-place on d_out ------
__global__ __launch_bounds__(256) void householder_ep(
    const float* __restrict__ x, const float* __restrict__ bias,
    float* __restrict__ vio, const float* __restrict__ V2,
    float* __restrict__ logdet) {
  const int row = blockIdx.x;
  const int t = threadIdx.x;
  float4* vr = (float4*)(vio + (size_t)row * N_DIM);
  const float4* xr = (const float4*)(x + (size_t)row * N_DIM);
  const float4* br = (const float4*)bias;

  float4 v = vr[t];
  if (V2) {
    float4 v2 = ((const float4*)(V2 + (size_t)row * N_DIM))[t];
    v.x += v2.x; v.y += v2.y; v.z += v2.z; v.w += v2.w;
  }
  float4 bb = br[t];
  v.x += bb.x; v.y += bb.y; v.z += bb.z; v.w += bb.w;
  float4 xx = xr[t];

  float dot = v.x * xx.x + v.y * xx.y + v.z * xx.z + v.w * xx.w;
  float nsq = v.x * v.x + v.y * v.y + v.z * v.z + v.w * v.w;

  #pragma unroll
  for (int off = 32; off > 0; off >>= 1) {
    dot += __shfl_down(dot, off);
    nsq += __shfl_down(nsq, off);
  }
  __shared__ float sd[4], sn[4];
  if ((t & 63) == 0) { sd[t >> 6] = dot; sn[t >> 6] = nsq; }
  __syncthreads();
  dot = sd[0] + sd[1] + sd[2] + sd[3];
  nsq = sn[0] + sn[1] + sn[2] + sn[3];

  const float f = 2.0f * dot / sqrtf(nsq);
  float4 o;
  o.x = xx.x - f * v.x;
  o.y = xx.y - f * v.y;
  o.z = xx.z - f * v.z;
  o.w = xx.w - f * v.w;
  vr[t] = o;
  if (t == 0) logdet[row] = 0.0f;
}

extern "C" void kernel_launch(void* const* d_in, const int* in_sizes, int n_in,
                              void* d_out, int out_size, void* d_ws, size_t ws_size,
                              hipStream_t stream) {
  const float* x   = (const float*)d_in[0];   // [8192,1024]
  const float* enc = (const float*)d_in[1];   // [8192,4096]
  const float* W   = (const float*)d_in[2];   // [1024,4096]
  const float* b   = (const float*)d_in[3];   // [1024]

  float* out    = (float*)d_out;
  float* v      = out;                              // V partial 0 lives in d_out
  float* logdet = out + (size_t)M_DIM * N_DIM;

  char*  packA = (char*)d_ws;                       // 64 MB
  char*  packB = packA + (size_t)64 * 1024 * 1024;  //  8 MB
  float* V2    = (float*)(packB + (size_t)8 * 1024 * 1024);  // 32 MB (split-K partial)

  const size_t need1 = (size_t)72 * 1024 * 1024;
  const size_t need2 = (size_t)104 * 1024 * 1024;
  const int nsplit = (ws_size >= need2) ? 2 : 1;    // round-1 proved ws >= 72MB

  pack_swz<<<(M_DIM * K_DIM / 8) / 256, 256, 0, stream>>>(enc, (int4*)packA);
  pack_swz<<<(N_DIM * K_DIM / 8) / 256, 256, 0, stream>>>(W, (int4*)packB);

  (void)need1;
  hipFuncSetAttribute((const void*)gemm8, hipFuncAttributeMaxDynamicSharedMemorySize, 131072);
  gemm8<<<dim3(128 * nsplit), 512, 131072, stream>>>(
      packA, packB, v, nsplit == 2 ? V2 : nullptr, 64 / nsplit);

  householder_ep<<<M_DIM, 256, 0, stream>>>(x, b, v, nsplit == 2 ? V2 : nullptr, logdet);
}

// Round 3
// 121.915 us; speedup vs baseline: 1.2209x; 1.0996x over previous
//
#include <hip/hip_runtime.h>
#include <hip/hip_bf16.h>
#include <stdint.h>

#define M_DIM 8192
#define N_DIM 1024
#define K_DIM 4096

typedef __bf16 bf16x8 __attribute__((ext_vector_type(8)));
typedef float f32x4 __attribute__((ext_vector_type(4)));
typedef __hip_bfloat16 bf16_t;

__device__ __forceinline__ void gload_lds16(const void* g, void* l) {
  __builtin_amdgcn_global_load_lds(
      (const __attribute__((address_space(1))) void*)g,
      (__attribute__((address_space(3))) void*)l, 16, 0, 0);
}

// ---- pack: fp32 [R][4096] -> bf16, tiled [rt][kt][256 rows][8 chunks], with
// st-swizzle pre-applied (chunk' = chunk ^ (row&7)) so GEMM staging is linear
// and swizzled ds_reads are conflict-free (rule #21). enc+W in one launch.
__global__ __launch_bounds__(256) void pack_both(const float* __restrict__ enc,
                                                 const float* __restrict__ W,
                                                 int4* __restrict__ pA,
                                                 int4* __restrict__ pB) {
  const unsigned gtid = blockIdx.x * 256 + threadIdx.x;
  const float* src;
  int4* dst;
  unsigned t;
  if (gtid < 4194304u) { src = enc; dst = pA; t = gtid; }          // 8192*4096/8
  else                 { src = W;   dst = pB; t = gtid - 4194304u; }
  const unsigned cp = t & 7;
  const unsigned tmp = t >> 3;
  const unsigned r = tmp & 255;
  const unsigned tmp2 = tmp >> 8;
  const unsigned kt = tmp2 & 63;
  const unsigned rt = tmp2 >> 6;
  const unsigned srow = (rt << 8) + r;
  const unsigned k0 = (kt << 6) + ((cp ^ (r & 7)) << 3);
  const float4* s = (const float4*)(src + (size_t)srow * 4096 + k0);
  float4 a = s[0], b = s[1];
  union { bf16_t h[8]; int4 v; } u;
  u.h[0] = __float2bfloat16(a.x); u.h[1] = __float2bfloat16(a.y);
  u.h[2] = __float2bfloat16(a.z); u.h[3] = __float2bfloat16(a.w);
  u.h[4] = __float2bfloat16(b.x); u.h[5] = __float2bfloat16(b.y);
  u.h[6] = __float2bfloat16(b.z); u.h[7] = __float2bfloat16(b.w);
  dst[t] = u.v;
}

// ---- 8-phase 256x256 GEMM with cross-phase operand residency ----------------
// 512 thr = 8 waves (2M x 4N), per-wave C = 128x64. Snake order M0N0 -> M0N1
// -> M1N1 -> M1N0 keeps A resident across P0-P1 / P2-P3 and B(N1) across
// P1-P2; B(N0) held in its own regs from P0 to P3. 24 ds_read_b128 / K-tile
// (vs 48 naive) -> MFMA-bound. Counted vmcnt(4), setprio around MFMA.
__device__ __forceinline__ void stage_half(const char* g, char* smem, int ldsoff, int tid) {
  gload_lds16(g + tid * 16, smem + ldsoff + tid * 16);
  gload_lds16(g + 8192 + tid * 16, smem + ldsoff + 8192 + tid * 16);
}

__global__ __launch_bounds__(512, 2) void gemm8(
    const char* __restrict__ pA, const char* __restrict__ pB,
    float* __restrict__ V0, float* __restrict__ V1p, int NT) {
  extern __shared__ char smem[];
  const int tid = threadIdx.x;
  const int lane = tid & 63, wave = tid >> 6;
  const int wm = wave >> 2, wn = wave & 3;
  const int lrow = lane & 15, lkc = lane >> 4;

  // XCD-aware swizzle (grid is 128 or 256 -> % 8 == 0, bijective)
  const int cpx = (int)gridDim.x >> 3;
  const int swz = ((int)blockIdx.x & 7) * cpx + ((int)blockIdx.x >> 3);
  const int split = swz >> 7;
  const int rem = swz & 127;
  const int mt = rem >> 2, nt = rem & 3;

  const char* Abase = pA + ((size_t)mt * 64 + (size_t)split * NT) * 32768;
  const char* Bbase = pB + ((size_t)nt * 64 + (size_t)split * NT) * 32768;
  float* V = split ? V1p : V0;

  // Per-lane LDS read offsets. Note (row & 7) == (lrow & 7) for every
  // fragment row (all other row terms are multiples of 8), so the swizzle
  // xor folds into two per-lane constants.
  int colw[2];
  colw[0] = ((lkc) ^ (lrow & 7)) << 4;
  colw[1] = ((4 + lkc) ^ (lrow & 7)) << 4;
  int aRow[4], bRow[2];
  #pragma unroll
  for (int f = 0; f < 4; ++f) aRow[f] = (wm * 64 + f * 16 + lrow) * 128;
  #pragma unroll
  for (int f2 = 0; f2 < 2; ++f2) bRow[f2] = 32768 + (wn * 32 + f2 * 16 + lrow) * 128;

  f32x4 acc[2][4][2][2];
  #pragma unroll
  for (int a0 = 0; a0 < 2; ++a0)
    #pragma unroll
    for (int a1 = 0; a1 < 4; ++a1)
      #pragma unroll
      for (int a2 = 0; a2 < 2; ++a2)
        #pragma unroll
        for (int a3 = 0; a3 < 2; ++a3)
          acc[a0][a1][a2][a3] = (f32x4){0.f, 0.f, 0.f, 0.f};

  const int ktm = NT - 1;

  // Prologue: Ah0(0), Bh1(0), Ah1(0), Bh0(0), Ah0(1), Bh1(1)
  stage_half(Abase, smem, 0, tid);
  stage_half(Bbase + 16384, smem, 32768 + 16384, tid);
  stage_half(Abase + 16384, smem, 16384, tid);
  stage_half(Bbase, smem, 32768, tid);
  stage_half(Abase + 32768, smem, 65536, tid);
  stage_half(Bbase + 32768 + 16384, smem, 65536 + 32768 + 16384, tid);
  asm volatile("s_waitcnt vmcnt(4)" ::: "memory");
  __builtin_amdgcn_s_barrier();

  for (int g = 0; g < NT; ++g) {
    const int bb = g & 1, nbf = bb ^ 1;
    char* ab = smem + bb * 65536;
    const char* A1t = Abase + (size_t)((g + 1) & ktm) * 32768;
    const char* B1t = Bbase + (size_t)((g + 1) & ktm) * 32768;
    const char* A2t = Abase + (size_t)((g + 2) & ktm) * 32768;
    const char* B2t = Bbase + (size_t)((g + 2) & ktm) * 32768;

    bf16x8 a[4][2], b0[2][2], b1[2][2];

    // ---- P0: read A(M0) + B(N0); stage Ah1(g+1); MFMA M0N0 ----
    #pragma unroll
    for (int f = 0; f < 4; ++f)
      #pragma unroll
      for (int s = 0; s < 2; ++s)
        a[f][s] = *(const bf16x8*)(ab + aRow[f] + colw[s]);
    #pragma unroll
    for (int f2 = 0; f2 < 2; ++f2)
      #pragma unroll
      for (int s = 0; s < 2; ++s)
        b0[f2][s] = *(const bf16x8*)(ab + bRow[f2] + colw[s]);
    stage_half(A1t + 16384, smem, nbf * 65536 + 16384, tid);
    __builtin_amdgcn_sched_barrier(0);
    __builtin_amdgcn_s_barrier();
    asm volatile("s_waitcnt lgkmcnt(0)" ::: "memory");
    __builtin_amdgcn_sched_barrier(0);
    __builtin_amdgcn_s_setprio(1);
    #pragma unroll
    for (int f = 0; f < 4; ++f)
      #pragma unroll
      for (int f2 = 0; f2 < 2; ++f2)
        #pragma unroll
        for (int s = 0; s < 2; ++s)
          acc[0][f][0][f2] = __builtin_amdgcn_mfma_f32_16x16x32_bf16(
              a[f][s], b0[f2][s], acc[0][f][0][f2], 0, 0, 0);
    __builtin_amdgcn_s_setprio(0);
    __builtin_amdgcn_sched_barrier(0);
    __builtin_amdgcn_s_barrier();

    // ---- P1: read B(N1) only (A resident); stage Bh0(g+1); MFMA M0N1 ----
    #pragma unroll
    for (int f2 = 0; f2 < 2; ++f2)
      #pragma unroll
      for (int s = 0; s < 2; ++s)
        b1[f2][s] = *(const bf16x8*)(ab + bRow[f2] + 16384 + colw[s]);
    stage_half(B1t, smem, nbf * 65536 + 32768, tid);
    __builtin_amdgcn_sched_barrier(0);
    __builtin_amdgcn_s_barrier();
    asm volatile("s_waitcnt lgkmcnt(0)" ::: "memory");
    __builtin_amdgcn_sched_barrier(0);
    __builtin_amdgcn_s_setprio(1);
    #pragma unroll
    for (int f = 0; f < 4; ++f)
      #pragma unroll
      for (int f2 = 0; f2 < 2; ++f2)
        #pragma unroll
        for (int s = 0; s < 2; ++s)
          acc[0][f][1][f2] = __builtin_amdgcn_mfma_f32_16x16x32_bf16(
              a[f][s], b1[f2][s], acc[0][f][1][f2], 0, 0, 0);
    __builtin_amdgcn_s_setprio(0);
    __builtin_amdgcn_sched_barrier(0);
    __builtin_amdgcn_s_barrier();

    // ---- P2: read A(M1) only (B(N1) resident); stage Ah0(g+2); MFMA M1N1 ----
    #pragma unroll
    for (int f = 0; f < 4; ++f)
      #pragma unroll
      for (int s = 0; s < 2; ++s)
        a[f][s] = *(const bf16x8*)(ab + aRow[f] + 16384 + colw[s]);
    stage_half(A2t, smem, bb * 65536, tid);
    __builtin_amdgcn_sched_barrier(0);
    __builtin_amdgcn_s_barrier();
    asm volatile("s_waitcnt lgkmcnt(0)" ::: "memory");
    __builtin_amdgcn_sched_barrier(0);
    __builtin_amdgcn_s_setprio(1);
    #pragma unroll
    for (int f = 0; f < 4; ++f)
      #pragma unroll
      for (int f2 = 0; f2 < 2; ++f2)
        #pragma unroll
        for (int s = 0; s < 2; ++s)
          acc[1][f][1][f2] = __builtin_amdgcn_mfma_f32_16x16x32_bf16(
              a[f][s], b1[f2][s], acc[1][f][1][f2], 0, 0, 0);
    __builtin_amdgcn_s_setprio(0);
    __builtin_amdgcn_sched_barrier(0);
    __builtin_amdgcn_s_barrier();

    // ---- P3: no reads (A(M1), B(N0) resident); stage Bh1(g+2); MFMA M1N0 ----
    stage_half(B2t + 16384, smem, bb * 65536 + 32768 + 16384, tid);
    __builtin_amdgcn_sched_barrier(0);
    __builtin_amdgcn_s_barrier();
    __builtin_amdgcn_s_setprio(1);
    #pragma unroll
    for (int f = 0; f < 4; ++f)
      #pragma unroll
      for (int f2 = 0; f2 < 2; ++f2)
        #pragma unroll
        for (int s = 0; s < 2; ++s)
          acc[1][f][0][f2] = __builtin_amdgcn_mfma_f32_16x16x32_bf16(
              a[f][s], b0[f2][s], acc[1][f][0][f2], 0, 0, 0);
    __builtin_amdgcn_s_setprio(0);
    asm volatile("s_waitcnt vmcnt(4)" ::: "memory");
    __builtin_amdgcn_sched_barrier(0);
    __builtin_amdgcn_s_barrier();
  }

  // C-write: frag layout col=lane&15, row=(lane>>4)*4+reg (m89-verified).
  // reg outer / cols inner so consecutive stores merge within the same rows.
  const int lq = lane >> 4;
  #pragma unroll
  for (int qm = 0; qm < 2; ++qm)
    #pragma unroll
    for (int f = 0; f < 4; ++f) {
      const int rowg = mt * 256 + qm * 128 + wm * 64 + f * 16 + lq * 4;
      #pragma unroll
      for (int reg = 0; reg < 4; ++reg) {
        float* Vr = V + (size_t)(rowg + reg) * N_DIM + nt * 256 + wn * 32 + lrow;
        #pragma unroll
        for (int qn = 0; qn < 2; ++qn)
          #pragma unroll
          for (int f2 = 0; f2 < 2; ++f2)
            Vr[qn * 128 + f2 * 16] = acc[qm][f][qn][f2][reg];
      }
    }
}

// ---- Householder epilogue: combines split-K partials, in-place on d_out ------
__global__ __launch_bounds__(256) void householder_ep(
    const float* __restrict__ x, const float* __restrict__ bias,
    float* __restrict__ vio, const float* __restrict__ V2,
    float* __restrict__ logdet) {
  const int row = blockIdx.x;
  const int t = threadIdx.x;
  float4* vr = (float4*)(vio + (size_t)row * N_DIM);
  const float4* xr = (const float4*)(x + (size_t)row * N_DIM);
  const float4* br = (const float4*)bias;

  float4 v = vr[t];
  if (V2) {
    float4 v2 = ((const float4*)(V2 + (size_t)row * N_DIM))[t];
    v.x += v2.x; v.y += v2.y; v.z += v2.z; v.w += v2.w;
  }
  float4 bb = br[t];
  v.x += bb.x; v.y += bb.y; v.z += bb.z; v.w += bb.w;
  float4 xx = xr[t];

  float dot = v.x * xx.x + v.y * xx.y + v.z * xx.z + v.w * xx.w;
  float nsq = v.x * v.x + v.y * v.y + v.z * v.z + v.w * v.w;

  #pragma unroll
  for (int off = 32; off > 0; off >>= 1) {
    dot += __shfl_down(dot, off);
    nsq += __shfl_down(nsq, off);
  }
  __shared__ float sd[4], sn[4];
  if ((t & 63) == 0) { sd[t >> 6] = dot; sn[t >> 6] = nsq; }
  __syncthreads();
  dot = sd[0] + sd[1] + sd[2] + sd[3];
  nsq = sn[0] + sn[1] + sn[2] + sn[3];

  const float f = 2.0f * dot / sqrtf(nsq);
  float4 o;
  o.x = xx.x - f * v.x;
  o.y = xx.y - f * v.y;
  o.z = xx.z - f * v.z;
  o.w = xx.w - f * v.w;
  vr[t] = o;
  if (t == 0) logdet[row] = 0.0f;
}

extern "C" void kernel_launch(void* const* d_in, const int* in_sizes, int n_in,
                              void* d_out, int out_size, void* d_ws, size_t ws_size,
                              hipStream_t stream) {
  const float* x   = (const float*)d_in[0];   // [8192,1024]
  const float* enc = (const float*)d_in[1];   // [8192,4096]
  const float* W   = (const float*)d_in[2];   // [1024,4096]
  const float* b   = (const float*)d_in[3];   // [1024]

  float* out    = (float*)d_out;
  float* v      = out;                              // V partial 0 lives in d_out
  float* logdet = out + (size_t)M_DIM * N_DIM;

  char*  packA = (char*)d_ws;                       // 64 MB
  char*  packB = packA + (size_t)64 * 1024 * 1024;  //  8 MB
  float* V2    = (float*)(packB + (size_t)8 * 1024 * 1024);  // 32 MB

  const size_t need2 = (size_t)104 * 1024 * 1024;
  const int nsplit = (ws_size >= need2) ? 2 : 1;

  pack_both<<<18432, 256, 0, stream>>>(enc, W, (int4*)packA, (int4*)packB);

  hipFuncSetAttribute((const void*)gemm8, hipFuncAttributeMaxDynamicSharedMemorySize, 131072);
  gemm8<<<dim3(128 * nsplit), 512, 131072, stream>>>(
      packA, packB, v, nsplit == 2 ? V2 : nullptr, 64 / nsplit);

  householder_ep<<<M_DIM, 256, 0, stream>>>(x, b, v, nsplit == 2 ? V2 : nullptr, logdet);
}

// Round 4
// 113.013 us; speedup vs baseline: 1.3170x; 1.0788x over previous
//
#include <hip/hip_runtime.h>
#include <hip/hip_bf16.h>
#include <stdint.h>

#define M_DIM 8192
#define N_DIM 1024
#define K_DIM 4096

typedef __bf16 bf16x8 __attribute__((ext_vector_type(8)));
typedef float f32x4 __attribute__((ext_vector_type(4)));
typedef __hip_bfloat16 bf16_t;

__device__ __forceinline__ void gload_lds16(const void* g, void* l) {
  __builtin_amdgcn_global_load_lds(
      (const __attribute__((address_space(1))) void*)g,
      (__attribute__((address_space(3))) void*)l, 16, 0, 0);
}

// ---- pack W only: fp32 [1024][4096] -> bf16 tiled [rt][kt][256 rows][8 chunks]
// with st-swizzle pre-applied (chunk' = chunk ^ (row&7)).
__global__ __launch_bounds__(256) void pack_w(const float* __restrict__ W,
                                              int4* __restrict__ pB) {
  const unsigned t = blockIdx.x * 256 + threadIdx.x;   // < 524288
  const unsigned cp = t & 7;
  const unsigned tmp = t >> 3;
  const unsigned r = tmp & 255;
  const unsigned tmp2 = tmp >> 8;
  const unsigned kt = tmp2 & 63;
  const unsigned rt = tmp2 >> 6;
  const unsigned srow = (rt << 8) + r;
  const unsigned k0 = (kt << 6) + ((cp ^ (r & 7)) << 3);
  const float4* s = (const float4*)(W + (size_t)srow * 4096 + k0);
  float4 a = s[0], b = s[1];
  union { bf16_t h[8]; int4 v; } u;
  u.h[0] = __float2bfloat16(a.x); u.h[1] = __float2bfloat16(a.y);
  u.h[2] = __float2bfloat16(a.z); u.h[3] = __float2bfloat16(a.w);
  u.h[4] = __float2bfloat16(b.x); u.h[5] = __float2bfloat16(b.y);
  u.h[6] = __float2bfloat16(b.z); u.h[7] = __float2bfloat16(b.w);
  pB[t] = u.v;
}

// ---- 8-phase 256x256 GEMM, A reg-staged from raw fp32 (no pack-A) ------------
// 512 thr = 8 waves (2M x 4N), per-wave C = 128x64, snake residency (r3).
// A: global fp32 -> regs (issued 1.5 phases early) -> cvt bf16 -> swizzled
// ds_write_b128 x2. B: packed bf16 via global_load_lds. Counted vmcnt ledger:
// entry invariant [gbx4, Bh1x2]; waits vmcnt(2)@P0-tail, vmcnt(2)@P2-tail,
// vmcnt(6)@P3-end. ds_write visibility: every write has a writer-lgkm-drain ->
// barrier pair before its first reader (Ah1: write P0, drain P1-lgkm, read
// P2(g+1); Ah0: write P2, drain P0(g+1)-lgkm, read P0(g+2)).
__device__ __forceinline__ void stage_half(const char* g, char* smem, int ldsoff, int tid) {
  gload_lds16(g + tid * 16, smem + ldsoff + tid * 16);
  gload_lds16(g + 8192 + tid * 16, smem + ldsoff + 8192 + tid * 16);
}

__device__ __forceinline__ void issue4(const float* g, float4* r) {
  const float4* s = (const float4*)g;
  r[0] = s[0]; r[1] = s[1]; r[2] = s[2]; r[3] = s[3];
}

__device__ __forceinline__ void cvt_write(const float4* r, char* base, int o0) {
  union { bf16_t h[8]; int4 v; } u0, u1;
  u0.h[0] = __float2bfloat16(r[0].x); u0.h[1] = __float2bfloat16(r[0].y);
  u0.h[2] = __float2bfloat16(r[0].z); u0.h[3] = __float2bfloat16(r[0].w);
  u0.h[4] = __float2bfloat16(r[1].x); u0.h[5] = __float2bfloat16(r[1].y);
  u0.h[6] = __float2bfloat16(r[1].z); u0.h[7] = __float2bfloat16(r[1].w);
  u1.h[0] = __float2bfloat16(r[2].x); u1.h[1] = __float2bfloat16(r[2].y);
  u1.h[2] = __float2bfloat16(r[2].z); u1.h[3] = __float2bfloat16(r[2].w);
  u1.h[4] = __float2bfloat16(r[3].x); u1.h[5] = __float2bfloat16(r[3].y);
  u1.h[6] = __float2bfloat16(r[3].z); u1.h[7] = __float2bfloat16(r[3].w);
  *(int4*)(base + o0) = u0.v;
  *(int4*)(base + (o0 ^ 16)) = u1.v;
}

__global__ __launch_bounds__(512, 2) void gemm8(
    const float* __restrict__ Araw, const char* __restrict__ pB,
    float* __restrict__ V0, float* __restrict__ V1p, int NT) {
  extern __shared__ char smem[];
  const int tid = threadIdx.x;
  const int lane = tid & 63, wave = tid >> 6;
  const int wm = wave >> 2, wn = wave & 3;
  const int lrow = lane & 15, lkc = lane >> 4;

  const int cpx = (int)gridDim.x >> 3;
  const int swz = ((int)blockIdx.x & 7) * cpx + ((int)blockIdx.x >> 3);
  const int split = swz >> 7;
  const int rem = swz & 127;
  const int mt = rem >> 2, nt = rem & 3;

  const char* Bbase = pB + ((size_t)nt * 64 + (size_t)split * NT) * 32768;
  float* V = split ? V1p : V0;

  // A global source: thread handles row (tid>>2) of the 128-row half,
  // 16 floats starting at col (tid&3)*16 of the 64-col K-step.
  const float* aG = Araw + (size_t)(mt * 256 + (tid >> 2)) * K_DIM +
                    (size_t)split * (NT * 64) + (tid & 3) * 16;
  // Swizzled LDS write offset within a half-slot (2-way bank alias = free).
  const int wrO0 = (tid >> 2) * 128 + ((((tid & 3) << 1) ^ ((tid >> 2) & 7)) << 4);

  int colw[2];
  colw[0] = ((lkc) ^ (lrow & 7)) << 4;
  colw[1] = ((4 + lkc) ^ (lrow & 7)) << 4;
  int aRow[4], bRow[2];
  #pragma unroll
  for (int f = 0; f < 4; ++f) aRow[f] = (wm * 64 + f * 16 + lrow) * 128;
  #pragma unroll
  for (int f2 = 0; f2 < 2; ++f2) bRow[f2] = 32768 + (wn * 32 + f2 * 16 + lrow) * 128;

  f32x4 acc[2][4][2][2];
  #pragma unroll
  for (int a0 = 0; a0 < 2; ++a0)
    #pragma unroll
    for (int a1 = 0; a1 < 4; ++a1)
      #pragma unroll
      for (int a2 = 0; a2 < 2; ++a2)
        #pragma unroll
        for (int a3 = 0; a3 < 2; ++a3)
          acc[a0][a1][a2][a3] = (f32x4){0.f, 0.f, 0.f, 0.f};

  const int ktm = NT - 1;
  float4 ga[4], gb[4];

  // ---- Prologue: tile0 complete + Ah0(1); end with [gb(Ah1(1))x4, Bh1(1)x2].
  issue4(aG, ga);                                         // A0 h0
  issue4(aG + 128 * K_DIM, gb);                           // A0 h1
  stage_half(Bbase, smem, 32768, tid);                    // B0 h0
  stage_half(Bbase + 16384, smem, 32768 + 16384, tid);    // B0 h1
  asm volatile("s_waitcnt vmcnt(4)" ::: "memory");
  cvt_write(ga, smem + 0, wrO0);                          // Ah0(0)
  cvt_write(gb, smem + 16384, wrO0);                      // Ah1(0)
  issue4(aG + 64, ga);                                    // A1 h0
  issue4(aG + 64 + 128 * K_DIM, gb);                      // A1 h1
  stage_half(Bbase + 32768 + 16384, smem, 65536 + 32768 + 16384, tid);  // B1 h1
  asm volatile("s_waitcnt vmcnt(6)" ::: "memory");
  cvt_write(ga, smem + 65536, wrO0);                      // Ah0(1)
  asm volatile("s_waitcnt lgkmcnt(0)" ::: "memory");
  __builtin_amdgcn_s_barrier();

  for (int g = 0; g < NT; ++g) {
    const int bb = g & 1, nbf = bb ^ 1;
    char* ab = smem + bb * 65536;
    const char* B1t = Bbase + (size_t)((g + 1) & ktm) * 32768;
    const char* B2t = Bbase + (size_t)((g + 2) & ktm) * 32768;
    const float* aP = aG + (size_t)((g + 2) & ktm) * 64;

    bf16x8 a[4][2], b0[2][2], b1[2][2];

    // ---- P0: reads A(M0)+B(N0); MFMA M0N0; tail: write Ah1(g+1) from gb ----
    #pragma unroll
    for (int f = 0; f < 4; ++f)
      #pragma unroll
      for (int s = 0; s < 2; ++s)
        a[f][s] = *(const bf16x8*)(ab + aRow[f] + colw[s]);
    #pragma unroll
    for (int f2 = 0; f2 < 2; ++f2)
      #pragma unroll
      for (int s = 0; s < 2; ++s)
        b0[f2][s] = *(const bf16x8*)(ab + bRow[f2] + colw[s]);
    __builtin_amdgcn_sched_barrier(0);
    __builtin_amdgcn_s_barrier();
    asm volatile("s_waitcnt lgkmcnt(0)" ::: "memory");
    __builtin_amdgcn_sched_barrier(0);
    __builtin_amdgcn_s_setprio(1);
    #pragma unroll
    for (int f = 0; f < 4; ++f)
      #pragma unroll
      for (int f2 = 0; f2 < 2; ++f2)
        #pragma unroll
        for (int s = 0; s < 2; ++s)
          acc[0][f][0][f2] = __builtin_amdgcn_mfma_f32_16x16x32_bf16(
              a[f][s], b0[f2][s], acc[0][f][0][f2], 0, 0, 0);
    __builtin_amdgcn_s_setprio(0);
    asm volatile("s_waitcnt vmcnt(2)" ::: "memory");
    cvt_write(gb, smem + nbf * 65536 + 16384, wrO0);      // Ah1(g+1)
    __builtin_amdgcn_sched_barrier(0);
    __builtin_amdgcn_s_barrier();

    // ---- P1: reads B(N1); issue ga(Ah0(g+2)); stage Bh0(g+1); MFMA M0N1 ----
    #pragma unroll
    for (int f2 = 0; f2 < 2; ++f2)
      #pragma unroll
      for (int s = 0; s < 2; ++s)
        b1[f2][s] = *(const bf16x8*)(ab + bRow[f2] + 16384 + colw[s]);
    issue4(aP, ga);
    stage_half(B1t, smem, nbf * 65536 + 32768, tid);
    __builtin_amdgcn_sched_barrier(0);
    __builtin_amdgcn_s_barrier();
    asm volatile("s_waitcnt lgkmcnt(0)" ::: "memory");
    __builtin_amdgcn_sched_barrier(0);
    __builtin_amdgcn_s_setprio(1);
    #pragma unroll
    for (int f = 0; f < 4; ++f)
      #pragma unroll
      for (int f2 = 0; f2 < 2; ++f2)
        #pragma unroll
        for (int s = 0; s < 2; ++s)
          acc[0][f][1][f2] = __builtin_amdgcn_mfma_f32_16x16x32_bf16(
              a[f][s], b1[f2][s], acc[0][f][1][f2], 0, 0, 0);
    __builtin_amdgcn_s_setprio(0);
    __builtin_amdgcn_sched_barrier(0);
    __builtin_amdgcn_s_barrier();

    // ---- P2: reads A(M1); MFMA M1N1; tail: write Ah0(g+2) from ga ----
    #pragma unroll
    for (int f = 0; f < 4; ++f)
      #pragma unroll
      for (int s = 0; s < 2; ++s)
        a[f][s] = *(const bf16x8*)(ab + aRow[f] + 16384 + colw[s]);
    __builtin_amdgcn_sched_barrier(0);
    __builtin_amdgcn_s_barrier();
    asm volatile("s_waitcnt lgkmcnt(0)" ::: "memory");
    __builtin_amdgcn_sched_barrier(0);
    __builtin_amdgcn_s_setprio(1);
    #pragma unroll
    for (int f = 0; f < 4; ++f)
      #pragma unroll
      for (int f2 = 0; f2 < 2; ++f2)
        #pragma unroll
        for (int s = 0; s < 2; ++s)
          acc[1][f][1][f2] = __builtin_amdgcn_mfma_f32_16x16x32_bf16(
              a[f][s], b1[f2][s], acc[1][f][1][f2], 0, 0, 0);
    __builtin_amdgcn_s_setprio(0);
    asm volatile("s_waitcnt vmcnt(2)" ::: "memory");
    cvt_write(ga, smem + bb * 65536, wrO0);               // Ah0(g+2)
    __builtin_amdgcn_sched_barrier(0);
    __builtin_amdgcn_s_barrier();

    // ---- P3: issue gb(Ah1(g+2)); stage Bh1(g+2); MFMA M1N0; end vmcnt(6) ----
    issue4(aP + 128 * K_DIM, gb);
    stage_half(B2t + 16384, smem, bb * 65536 + 32768 + 16384, tid);
    __builtin_amdgcn_sched_barrier(0);
    __builtin_amdgcn_s_barrier();
    __builtin_amdgcn_s_setprio(1);
    #pragma unroll
    for (int f = 0; f < 4; ++f)
      #pragma unroll
      for (int f2 = 0; f2 < 2; ++f2)
        #pragma unroll
        for (int s = 0; s < 2; ++s)
          acc[1][f][0][f2] = __builtin_amdgcn_mfma_f32_16x16x32_bf16(
              a[f][s], b0[f2][s], acc[1][f][0][f2], 0, 0, 0);
    __builtin_amdgcn_s_setprio(0);
    asm volatile("s_waitcnt vmcnt(6)" ::: "memory");
    __builtin_amdgcn_sched_barrier(0);
    __builtin_amdgcn_s_barrier();
  }

  // C-write: frag layout col=lane&15, row=(lane>>4)*4+reg (m89-verified).
  const int lq = lane >> 4;
  #pragma unroll
  for (int qm = 0; qm < 2; ++qm)
    #pragma unroll
    for (int f = 0; f < 4; ++f) {
      const int rowg = mt * 256 + qm * 128 + wm * 64 + f * 16 + lq * 4;
      #pragma unroll
      for (int reg = 0; reg < 4; ++reg) {
        float* Vr = V + (size_t)(rowg + reg) * N_DIM + nt * 256 + wn * 32 + lrow;
        #pragma unroll
        for (int qn = 0; qn < 2; ++qn)
          #pragma unroll
          for (int f2 = 0; f2 < 2; ++f2)
            Vr[qn * 128 + f2 * 16] = acc[qm][f][qn][f2][reg];
      }
    }
}

// ---- Householder epilogue: combines split-K partials, in-place on d_out ------
__global__ __launch_bounds__(256) void householder_ep(
    const float* __restrict__ x, const float* __restrict__ bias,
    float* __restrict__ vio, const float* __restrict__ V2,
    float* __restrict__ logdet) {
  const int row = blockIdx.x;
  const int t = threadIdx.x;
  float4* vr = (float4*)(vio + (size_t)row * N_DIM);
  const float4* xr = (const float4*)(x + (size_t)row * N_DIM);
  const float4* br = (const float4*)bias;

  float4 v = vr[t];
  if (V2) {
    float4 v2 = ((const float4*)(V2 + (size_t)row * N_DIM))[t];
    v.x += v2.x; v.y += v2.y; v.z += v2.z; v.w += v2.w;
  }
  float4 bb = br[t];
  v.x += bb.x; v.y += bb.y; v.z += bb.z; v.w += bb.w;
  float4 xx = xr[t];

  float dot = v.x * xx.x + v.y * xx.y + v.z * xx.z + v.w * xx.w;
  float nsq = v.x * v.x + v.y * v.y + v.z * v.z + v.w * v.w;

  #pragma unroll
  for (int off = 32; off > 0; off >>= 1) {
    dot += __shfl_down(dot, off);
    nsq += __shfl_down(nsq, off);
  }
  __shared__ float sd[4], sn[4];
  if ((t & 63) == 0) { sd[t >> 6] = dot; sn[t >> 6] = nsq; }
  __syncthreads();
  dot = sd[0] + sd[1] + sd[2] + sd[3];
  nsq = sn[0] + sn[1] + sn[2] + sn[3];

  const float f = 2.0f * dot / sqrtf(nsq);
  float4 o;
  o.x = xx.x - f * v.x;
  o.y = xx.y - f * v.y;
  o.z = xx.z - f * v.z;
  o.w = xx.w - f * v.w;
  vr[t] = o;
  if (t == 0) logdet[row] = 0.0f;
}

extern "C" void kernel_launch(void* const* d_in, const int* in_sizes, int n_in,
                              void* d_out, int out_size, void* d_ws, size_t ws_size,
                              hipStream_t stream) {
  const float* x   = (const float*)d_in[0];   // [8192,1024]
  const float* enc = (const float*)d_in[1];   // [8192,4096]
  const float* W   = (const float*)d_in[2];   // [1024,4096]
  const float* b   = (const float*)d_in[3];   // [1024]

  float* out    = (float*)d_out;
  float* v      = out;                              // V partial 0 lives in d_out
  float* logdet = out + (size_t)M_DIM * N_DIM;

  char*  packB = (char*)d_ws;                               // 8 MB
  float* V2    = (float*)(packB + (size_t)8 * 1024 * 1024); // 32 MB

  const size_t need2 = (size_t)40 * 1024 * 1024;
  const int nsplit = (ws_size >= need2) ? 2 : 1;

  pack_w<<<2048, 256, 0, stream>>>(W, (int4*)packB);

  hipFuncSetAttribute((const void*)gemm8, hipFuncAttributeMaxDynamicSharedMemorySize, 131072);
  gemm8<<<dim3(128 * nsplit), 512, 131072, stream>>>(
      enc, packB, v, nsplit == 2 ? V2 : nullptr, 64 / nsplit);

  householder_ep<<<M_DIM, 256, 0, stream>>>(x, b, v, nsplit == 2 ? V2 : nullptr, logdet);
}